// Round 24
// baseline (171.521 us; speedup 1.0000x reference)
//
#include <hip/hip_runtime.h>

#define NP 16
#define D 768
#define NBLK 512   // 2 blocks/CU
#define NTHR 256   // 4 waves = 2 row-pair teams (K-split phase A)
#define RPI 32     // rows per block-iteration (2 teams x 16 rows)
#define DSL 192    // d-slice per wave in phase B
#define NM 12      // persistent accumulators

// ws float layout:
//  [0, 6144)        PTfrag (bf16 B-fragments of normalized protos)
//  [6144, 18432)    gsum[16][768] (atomic accumulator, zeroed by setup)
//  [18432, 18448)   gcnt[16]

typedef short short8 __attribute__((ext_vector_type(8)));
typedef float f32x4 __attribute__((ext_vector_type(4)));
typedef unsigned u32x2 __attribute__((ext_vector_type(2)));

#define LDS_OFF(ptr) ((unsigned)(size_t)(__attribute__((address_space(3))) const void*)(ptr))

static __device__ __forceinline__ unsigned f2bf_u(float f) {
    unsigned u = __float_as_uint(f);
    u += 0x7FFF + ((u >> 16) & 1);  // RTNE
    return u >> 16;
}
static __device__ __forceinline__ unsigned pack2bf(float lo, float hi) {
    return f2bf_u(lo) | (f2bf_u(hi) << 16);
}

__global__ __launch_bounds__(64) void setup_kernel(const float* __restrict__ protos,
                                                   float* __restrict__ ws) {
    const int p = blockIdx.x, lane = threadIdx.x;
    // zero this proto's slice of the atomic accumulators (every launch: ws is poisoned)
    float* gsum = ws + 6144 + p * D;
    for (int j = lane; j < D; j += 64) gsum[j] = 0.f;
    if (lane == 0) ws[18432 + p] = 0.f;

    const float* pr = protos + p * D;
    float v[12];
    float ns = 0.f;
#pragma unroll
    for (int j = 0; j < 12; ++j) {
        v[j] = pr[lane + 64 * j];
        ns = fmaf(v[j], v[j], ns);
    }
#pragma unroll
    for (int m = 1; m < 64; m <<= 1) ns += __shfl_xor(ns, m);
    const float rn = 1.0f / sqrtf(ns);
    // B-fragment scatter (verified r6-r23): Pn[p][c], c=s*32+g*8+jj -> ushort idx (s*64+g*16+p)*8+jj
    unsigned short* ptf = (unsigned short*)ws;
#pragma unroll
    for (int j = 0; j < 12; ++j) {
        const int c = lane + 64 * j;
        const int s = c >> 5, sub = c & 31, g = sub >> 3, jj = sub & 7;
        ptf[(unsigned)((s * 64 + g * 16 + p) * 8 + jj)] = (unsigned short)f2bf_u(v[j] * rn);
    }
}

__global__ __launch_bounds__(NTHR, 2) void fused_kernel(const float* __restrict__ x,
                                                        const float* __restrict__ ws,
                                                        float* __restrict__ gsum,
                                                        float* __restrict__ gcnt,
                                                        int nrows, int niter) {
    __shared__ unsigned short tileT[24576];  // 48 KB bf16 tile: [q8][cb48][rr4][cc16]
    __shared__ f32x4 simred[2][64];          // 2 KB: K-split partial sims
    __shared__ float normred[2][16];
    __shared__ float rS[RPI];
    __shared__ int aS[RPI];
    __shared__ float C[NP];

    const int tid = threadIdx.x, w = tid >> 6, lane = tid & 63;
    const int r15 = lane & 15, g = lane >> 4;
    const int tp = w >> 1, h = w & 1;  // row-pair team, col-half

    // preload this lane's 12 loop-invariant proto fragments into registers
    // (global, coalesced: lane l reads 16B at ((h*12+s)*64+l)*16)
    short8 pf[12];
    {
        const short8* pw = ((const short8*)ws) + lane;
#pragma unroll
        for (int s = 0; s < 12; ++s) pf[s] = pw[(h * 12 + s) * 64];
    }

    if (tid < NP) C[tid] = 0.f;
    __syncthreads();

    f32x4 acc[NM];
#pragma unroll
    for (int m = 0; m < NM; ++m) acc[m] = (f32x4){0.f, 0.f, 0.f, 0.f};

    for (int it = blockIdx.x; it < niter; it += NBLK) {
        const int rb = it * RPI;
        const int base = rb + tp * 16;

        // ---- phase A: K-split sim (wave h covers cols h*384..+383 of team tp's 16 rows),
        //      writes bf16 tile subtiled for tr_read; proto frags from registers ----
        const int rowc = min(base + r15, nrows - 1);
        const float* xr = x + (size_t)rowc * D + h * 384 + (g << 3);
        f32x4 sa = {0.f, 0.f, 0.f, 0.f};
        float nse = 0.f, nso = 0.f;
        const unsigned q = (unsigned)(tp * 4 + (r15 >> 2));
        const unsigned rr = (unsigned)(r15 & 3);
        const unsigned cc0 = (unsigned)((g & 1) * 8);
#pragma unroll
        for (int s = 0; s < 12; ++s) {
            const float4 f0 = *(const float4*)(xr + s * 32);
            const float4 f1 = *(const float4*)(xr + s * 32 + 4);
            nse = fmaf(f0.x, f0.x, fmaf(f0.y, f0.y, fmaf(f0.z, f0.z, fmaf(f0.w, f0.w, nse))));
            nso = fmaf(f1.x, f1.x, fmaf(f1.y, f1.y, fmaf(f1.z, f1.z, fmaf(f1.w, f1.w, nso))));
            uint4 au;
            au.x = pack2bf(f0.x, f0.y);
            au.y = pack2bf(f0.z, f0.w);
            au.z = pack2bf(f1.x, f1.y);
            au.w = pack2bf(f1.z, f1.w);
            const unsigned cb = (unsigned)(h * 24 + s * 2 + (g >> 1));
            *(uint4*)&tileT[((q * 48 + cb) * 4 + rr) * 16 + cc0] = au;
            sa = __builtin_amdgcn_mfma_f32_16x16x32_bf16(
                __builtin_bit_cast(short8, au), pf[s], sa, 0, 0, 0);
        }
        float ns = nse + nso;
        ns += __shfl_xor(ns, 16);
        ns += __shfl_xor(ns, 32);
        if (h == 1) {
            simred[tp][lane] = sa;
            if (lane < 16) normred[tp][lane] = ns;
        }
        __syncthreads();  // #1: halves + tile visible

        if (h == 0) {
            const f32x4 o = simred[tp][lane];
            f32x4 sc;
#pragma unroll
            for (int r = 0; r < 4; ++r) sc[r] = sa[r] + o[r];
            ns += normred[tp][r15];
            const float rn = 1.0f / sqrtf(ns);
            int ar[4];
#pragma unroll
            for (int r = 0; r < 4; ++r) {
                float bv = sc[r];
                int bi = r15;
#pragma unroll
                for (int m = 1; m <= 8; m <<= 1) {
                    const float ov = __shfl_xor(bv, m);
                    const int oi = __shfl_xor(bi, m);
                    if (ov > bv || (ov == bv && oi < bi)) { bv = ov; bi = oi; }
                }
                ar[r] = bi;
            }
            if (r15 == 0) {
#pragma unroll
                for (int r = 0; r < 4; ++r) {
                    aS[tp * 16 + g * 4 + r] = ar[r];
                    if (base + g * 4 + r < nrows) atomicAdd(&C[ar[r]], 1.0f);
                }
            }
            if (lane < 16) rS[tp * 16 + lane] = (base + lane < nrows) ? rn : 0.f;
        }
        __syncthreads();  // #2: aS/rS ready

        // ---- phase B: rn-weighted one-hot MFMA; B-frags via batched transpose reads ----
        // lane r15 fetches subtile bytes r15*8; permute net returns column r15 across 4 rows
        // (verified r20/r22). 8 tr_reads + ONE waitcnt per asm block (rule-18 safe).
        {
            const int nb = g << 3;
            unsigned hb[8];
#pragma unroll
            for (int j = 0; j < 8; ++j) {
                const int an = aS[nb + j];
                const unsigned rb16 = f2bf_u(rS[nb + j]);
                hb[j] = (an == r15) ? rb16 : 0u;
            }
            uint4 au;
            au.x = hb[0] | (hb[1] << 16);
            au.y = hb[2] | (hb[3] << 16);
            au.z = hb[4] | (hb[5] << 16);
            au.w = hb[6] | (hb[7] << 16);
            const short8 afrag = __builtin_bit_cast(short8, au);
            const unsigned qb = (unsigned)(g * 2);
            const unsigned lb = (unsigned)r15 * 4;
#pragma unroll
            for (int mg = 0; mg < 3; ++mg) {
                const unsigned cb0 = (unsigned)(w * 12 + mg * 4);
                u32x2 t[8];
                unsigned a[8];
#pragma unroll
                for (int mm = 0; mm < 4; ++mm) {
                    a[2 * mm] = LDS_OFF(&tileT[((qb + 0) * 48 + cb0 + mm) * 64 + lb]);
                    a[2 * mm + 1] = LDS_OFF(&tileT[((qb + 1) * 48 + cb0 + mm) * 64 + lb]);
                }
                asm volatile(
                    "ds_read_b64_tr_b16 %0, %8\n\t"
                    "ds_read_b64_tr_b16 %1, %9\n\t"
                    "ds_read_b64_tr_b16 %2, %10\n\t"
                    "ds_read_b64_tr_b16 %3, %11\n\t"
                    "ds_read_b64_tr_b16 %4, %12\n\t"
                    "ds_read_b64_tr_b16 %5, %13\n\t"
                    "ds_read_b64_tr_b16 %6, %14\n\t"
                    "ds_read_b64_tr_b16 %7, %15\n\t"
                    "s_waitcnt lgkmcnt(0)"
                    : "=&v"(t[0]), "=&v"(t[1]), "=&v"(t[2]), "=&v"(t[3]),
                      "=&v"(t[4]), "=&v"(t[5]), "=&v"(t[6]), "=&v"(t[7])
                    : "v"(a[0]), "v"(a[1]), "v"(a[2]), "v"(a[3]),
                      "v"(a[4]), "v"(a[5]), "v"(a[6]), "v"(a[7]));
#pragma unroll
                for (int mm = 0; mm < 4; ++mm) {
                    uint4 bu;
                    bu.x = t[2 * mm][0];
                    bu.y = t[2 * mm][1];
                    bu.z = t[2 * mm + 1][0];
                    bu.w = t[2 * mm + 1][1];
                    acc[mg * 4 + mm] = __builtin_amdgcn_mfma_f32_16x16x32_bf16(
                        afrag, __builtin_bit_cast(short8, bu), acc[mg * 4 + mm], 0, 0, 0);
                }
            }
        }
        __syncthreads();  // #3: tile/aS/rS safe to overwrite next iteration
    }

    // ---- flush: device-scope atomic adds into the single global accumulator ----
    // acc[m][r]: proto = g*4+r, d = w*DSL + m*16 + r15
#pragma unroll
    for (int m = 0; m < NM; ++m)
#pragma unroll
        for (int r = 0; r < 4; ++r)
            __hip_atomic_fetch_add(&gsum[(g * 4 + r) * D + w * DSL + m * 16 + r15],
                                   acc[m][r], __ATOMIC_RELAXED, __HIP_MEMORY_SCOPE_AGENT);
    if (tid < NP)
        __hip_atomic_fetch_add(&gcnt[tid], C[tid], __ATOMIC_RELAXED,
                               __HIP_MEMORY_SCOPE_AGENT);
}

__global__ __launch_bounds__(256) void finalize_kernel(const float* __restrict__ ws,
                                                       float* __restrict__ out) {
    const int i = blockIdx.x * 256 + threadIdx.x;
    if (i < NP * D) {
        const float c = ws[18432 + i / D];
        const float s = ws[6144 + i];
        out[i] = (c > 0.f) ? s / fmaxf(c, 1.0f) : 0.f;
    }
}

extern "C" void kernel_launch(void* const* d_in, const int* in_sizes, int n_in,
                              void* d_out, int out_size, void* d_ws, size_t ws_size,
                              hipStream_t stream) {
    const float* x = (const float*)d_in[0];
    const float* protos = (const float*)d_in[1];
    float* ws = (float*)d_ws;
    float* out = (float*)d_out;
    const int nrows = in_sizes[0] / D;             // 200000
    const int niter = (nrows + RPI - 1) / RPI;     // 6250 (exact: 6250*32 = 200000)

    setup_kernel<<<16, 64, 0, stream>>>(protos, ws);
    fused_kernel<<<NBLK, NTHR, 0, stream>>>(x, ws, ws + 6144, ws + 18432, nrows, niter);
    finalize_kernel<<<(NP * D + 255) / 256, 256, 0, stream>>>(ws, out);
}

// Round 25
// 132.917 us; speedup vs baseline: 1.2904x; 1.2904x over previous
//
#include <hip/hip_runtime.h>

#define NP 16
#define D 768
#define NBLK 512   // 2 blocks/CU (74.4 KB LDS each)
#define NTHR 256   // 4 waves = 2 row-pair teams (K-split phase A)
#define RPI 32     // rows per block-iteration (2 teams x 16 rows)
#define DSL 192    // d-slice per wave in phase B
#define NM 12      // persistent accumulators

// ws float layout:
//  [0, 6144)        PTfrag (bf16 B-fragments of normalized protos)
//  [6144, 18432)    gsum[16][768] (atomic accumulator, zeroed by setup)
//  [18432, 18448)   gcnt[16]

typedef short short8 __attribute__((ext_vector_type(8)));
typedef float f32x4 __attribute__((ext_vector_type(4)));
typedef unsigned u32x2 __attribute__((ext_vector_type(2)));

#define LDS_OFF(ptr) ((unsigned)(size_t)(__attribute__((address_space(3))) const void*)(ptr))

static __device__ __forceinline__ unsigned f2bf_u(float f) {
    unsigned u = __float_as_uint(f);
    u += 0x7FFF + ((u >> 16) & 1);  // RTNE
    return u >> 16;
}
static __device__ __forceinline__ unsigned pack2bf(float lo, float hi) {
    return f2bf_u(lo) | (f2bf_u(hi) << 16);
}

__global__ __launch_bounds__(64) void setup_kernel(const float* __restrict__ protos,
                                                   float* __restrict__ ws) {
    const int p = blockIdx.x, lane = threadIdx.x;
    // zero this proto's slice of the atomic accumulators (every launch: ws is poisoned)
    float* gsum = ws + 6144 + p * D;
    for (int j = lane; j < D; j += 64) gsum[j] = 0.f;
    if (lane == 0) ws[18432 + p] = 0.f;

    const float* pr = protos + p * D;
    float v[12];
    float ns = 0.f;
#pragma unroll
    for (int j = 0; j < 12; ++j) {
        v[j] = pr[lane + 64 * j];
        ns = fmaf(v[j], v[j], ns);
    }
#pragma unroll
    for (int m = 1; m < 64; m <<= 1) ns += __shfl_xor(ns, m);
    const float rn = 1.0f / sqrtf(ns);
    // B-fragment scatter (verified r6-r23): Pn[p][c], c=s*32+g*8+jj -> ushort idx (s*64+g*16+p)*8+jj
    unsigned short* ptf = (unsigned short*)ws;
#pragma unroll
    for (int j = 0; j < 12; ++j) {
        const int c = lane + 64 * j;
        const int s = c >> 5, sub = c & 31, g = sub >> 3, jj = sub & 7;
        ptf[(unsigned)((s * 64 + g * 16 + p) * 8 + jj)] = (unsigned short)f2bf_u(v[j] * rn);
    }
}

__global__ __launch_bounds__(NTHR, 2) void fused_kernel(const float* __restrict__ x,
                                                        const float* __restrict__ ws,
                                                        float* __restrict__ gsum,
                                                        float* __restrict__ gcnt,
                                                        int nrows, int niter) {
    __shared__ short8 sPT[24 * 64];          // 24 KB proto B-fragments
    __shared__ unsigned short tileT[24576];  // 48 KB bf16 tile: [q8][cb48][rr4][cc16]
    __shared__ f32x4 simred[2][64];          // 2 KB: K-split partial sims
    __shared__ float normred[2][16];
    __shared__ float rS[RPI];
    __shared__ int aS[RPI];
    __shared__ float C[NP];

    const int tid = threadIdx.x, w = tid >> 6, lane = tid & 63;
    const int r15 = lane & 15, g = lane >> 4;
    const int tp = w >> 1, h = w & 1;  // row-pair team, col-half

    {
        const uint4* src = (const uint4*)ws;
        uint4* dst = (uint4*)sPT;
        for (int i = tid; i < 1536; i += NTHR) dst[i] = src[i];
    }
    if (tid < NP) C[tid] = 0.f;
    __syncthreads();

    f32x4 acc[NM];
#pragma unroll
    for (int m = 0; m < NM; ++m) acc[m] = (f32x4){0.f, 0.f, 0.f, 0.f};

    for (int it = blockIdx.x; it < niter; it += NBLK) {
        const int rb = it * RPI;
        const int base = rb + tp * 16;

        // ---- phase A: K-split sim (wave h covers cols h*384..+383 of team tp's 16 rows),
        //      writes bf16 tile subtiled for tr_read ----
        const int rowc = min(base + r15, nrows - 1);
        const float* xr = x + (size_t)rowc * D + h * 384 + (g << 3);
        const short8* bp = sPT + lane;
        f32x4 sa = {0.f, 0.f, 0.f, 0.f};
        float nse = 0.f, nso = 0.f;
        const unsigned q = (unsigned)(tp * 4 + (r15 >> 2));
        const unsigned rr = (unsigned)(r15 & 3);
        const unsigned cc0 = (unsigned)((g & 1) * 8);
#pragma unroll
        for (int s = 0; s < 12; ++s) {
            const float4 f0 = *(const float4*)(xr + s * 32);
            const float4 f1 = *(const float4*)(xr + s * 32 + 4);
            nse = fmaf(f0.x, f0.x, fmaf(f0.y, f0.y, fmaf(f0.z, f0.z, fmaf(f0.w, f0.w, nse))));
            nso = fmaf(f1.x, f1.x, fmaf(f1.y, f1.y, fmaf(f1.z, f1.z, fmaf(f1.w, f1.w, nso))));
            uint4 au;
            au.x = pack2bf(f0.x, f0.y);
            au.y = pack2bf(f0.z, f0.w);
            au.z = pack2bf(f1.x, f1.y);
            au.w = pack2bf(f1.z, f1.w);
            const unsigned cb = (unsigned)(h * 24 + s * 2 + (g >> 1));
            *(uint4*)&tileT[((q * 48 + cb) * 4 + rr) * 16 + cc0] = au;
            sa = __builtin_amdgcn_mfma_f32_16x16x32_bf16(
                __builtin_bit_cast(short8, au), bp[(h * 12 + s) * 64], sa, 0, 0, 0);
        }
        float ns = nse + nso;
        ns += __shfl_xor(ns, 16);
        ns += __shfl_xor(ns, 32);
        if (h == 1) {
            simred[tp][lane] = sa;
            if (lane < 16) normred[tp][lane] = ns;
        }
        __syncthreads();  // #1: halves + tile visible

        if (h == 0) {
            const f32x4 o = simred[tp][lane];
            f32x4 sc;
#pragma unroll
            for (int r = 0; r < 4; ++r) sc[r] = sa[r] + o[r];
            ns += normred[tp][r15];
            const float rn = 1.0f / sqrtf(ns);
            int ar[4];
#pragma unroll
            for (int r = 0; r < 4; ++r) {
                float bv = sc[r];
                int bi = r15;
#pragma unroll
                for (int m = 1; m <= 8; m <<= 1) {
                    const float ov = __shfl_xor(bv, m);
                    const int oi = __shfl_xor(bi, m);
                    if (ov > bv || (ov == bv && oi < bi)) { bv = ov; bi = oi; }
                }
                ar[r] = bi;
            }
            if (r15 == 0) {
#pragma unroll
                for (int r = 0; r < 4; ++r) {
                    aS[tp * 16 + g * 4 + r] = ar[r];
                    if (base + g * 4 + r < nrows) atomicAdd(&C[ar[r]], 1.0f);
                }
            }
            if (lane < 16) rS[tp * 16 + lane] = (base + lane < nrows) ? rn : 0.f;
        }
        __syncthreads();  // #2: aS/rS ready

        // ---- phase B: rn-weighted one-hot MFMA; B-frags via batched transpose reads ----
        // lane r15 fetches subtile bytes r15*8; permute net returns column r15 across 4 rows
        // (verified r20/r22). 8 tr_reads + ONE waitcnt per asm block (rule-18 safe).
        {
            const int nb = g << 3;
            unsigned hb[8];
#pragma unroll
            for (int j = 0; j < 8; ++j) {
                const int an = aS[nb + j];
                const unsigned rb16 = f2bf_u(rS[nb + j]);
                hb[j] = (an == r15) ? rb16 : 0u;
            }
            uint4 au;
            au.x = hb[0] | (hb[1] << 16);
            au.y = hb[2] | (hb[3] << 16);
            au.z = hb[4] | (hb[5] << 16);
            au.w = hb[6] | (hb[7] << 16);
            const short8 afrag = __builtin_bit_cast(short8, au);
            const unsigned qb = (unsigned)(g * 2);
            const unsigned lb = (unsigned)r15 * 4;
#pragma unroll
            for (int mg = 0; mg < 3; ++mg) {
                const unsigned cb0 = (unsigned)(w * 12 + mg * 4);
                u32x2 t[8];
                unsigned a[8];
#pragma unroll
                for (int mm = 0; mm < 4; ++mm) {
                    a[2 * mm] = LDS_OFF(&tileT[((qb + 0) * 48 + cb0 + mm) * 64 + lb]);
                    a[2 * mm + 1] = LDS_OFF(&tileT[((qb + 1) * 48 + cb0 + mm) * 64 + lb]);
                }
                asm volatile(
                    "ds_read_b64_tr_b16 %0, %8\n\t"
                    "ds_read_b64_tr_b16 %1, %9\n\t"
                    "ds_read_b64_tr_b16 %2, %10\n\t"
                    "ds_read_b64_tr_b16 %3, %11\n\t"
                    "ds_read_b64_tr_b16 %4, %12\n\t"
                    "ds_read_b64_tr_b16 %5, %13\n\t"
                    "ds_read_b64_tr_b16 %6, %14\n\t"
                    "ds_read_b64_tr_b16 %7, %15\n\t"
                    "s_waitcnt lgkmcnt(0)"
                    : "=&v"(t[0]), "=&v"(t[1]), "=&v"(t[2]), "=&v"(t[3]),
                      "=&v"(t[4]), "=&v"(t[5]), "=&v"(t[6]), "=&v"(t[7])
                    : "v"(a[0]), "v"(a[1]), "v"(a[2]), "v"(a[3]),
                      "v"(a[4]), "v"(a[5]), "v"(a[6]), "v"(a[7]));
#pragma unroll
                for (int mm = 0; mm < 4; ++mm) {
                    uint4 bu;
                    bu.x = t[2 * mm][0];
                    bu.y = t[2 * mm][1];
                    bu.z = t[2 * mm + 1][0];
                    bu.w = t[2 * mm + 1][1];
                    acc[mg * 4 + mm] = __builtin_amdgcn_mfma_f32_16x16x32_bf16(
                        afrag, __builtin_bit_cast(short8, bu), acc[mg * 4 + mm], 0, 0, 0);
                }
            }
        }
        __syncthreads();  // #3: tile/aS/rS safe to overwrite next iteration
    }

    // ---- flush: device-scope atomic adds into the single global accumulator ----
    // acc[m][r]: proto = g*4+r, d = w*DSL + m*16 + r15
#pragma unroll
    for (int m = 0; m < NM; ++m)
#pragma unroll
        for (int r = 0; r < 4; ++r)
            __hip_atomic_fetch_add(&gsum[(g * 4 + r) * D + w * DSL + m * 16 + r15],
                                   acc[m][r], __ATOMIC_RELAXED, __HIP_MEMORY_SCOPE_AGENT);
    if (tid < NP)
        __hip_atomic_fetch_add(&gcnt[tid], C[tid], __ATOMIC_RELAXED,
                               __HIP_MEMORY_SCOPE_AGENT);
}

__global__ __launch_bounds__(256) void finalize_kernel(const float* __restrict__ ws,
                                                       float* __restrict__ out) {
    const int i = blockIdx.x * 256 + threadIdx.x;
    if (i < NP * D) {
        const float c = ws[18432 + i / D];
        const float s = ws[6144 + i];
        out[i] = (c > 0.f) ? s / fmaxf(c, 1.0f) : 0.f;
    }
}

extern "C" void kernel_launch(void* const* d_in, const int* in_sizes, int n_in,
                              void* d_out, int out_size, void* d_ws, size_t ws_size,
                              hipStream_t stream) {
    const float* x = (const float*)d_in[0];
    const float* protos = (const float*)d_in[1];
    float* ws = (float*)d_ws;
    float* out = (float*)d_out;
    const int nrows = in_sizes[0] / D;             // 200000
    const int niter = (nrows + RPI - 1) / RPI;     // 6250 (exact: 6250*32 = 200000)

    setup_kernel<<<16, 64, 0, stream>>>(protos, ws);
    fused_kernel<<<NBLK, NTHR, 0, stream>>>(x, ws, ws + 6144, ws + 18432, nrows, niter);
    finalize_kernel<<<(NP * D + 255) / 256, 256, 0, stream>>>(ws, out);
}